// Round 1
// baseline (626.788 us; speedup 1.0000x reference)
//
#include <hip/hip_runtime.h>
#include <math.h>

#define GMAX 128

// ---- problem constants -----------------------------------------------------
enum {
    NP0 = 138624, NP1 = 34656, NP2 = 8664,           // positions per scale (B*g*g*3)
    PB0 = (NP0 + 255) / 256,                         // 542
    PB1 = (NP1 + 255) / 256,                         // 136
    PB2 = (NP2 + 255) / 256,                         // 34
    PBT = PB0 + PB1 + PB2,                           // 712
    NE0 = NP0 * 85, NE1 = NP1 * 85, NE2 = NP2 * 85,  // elements per scale
    EB0 = (NE0 + 1023) / 1024,                       // 11507
    EB1 = (NE1 + 1023) / 1024,                       // 2877
    EB2 = (NE2 + 1023) / 1024,                       // 720
    EBT = EB0 + EB1 + EB2                            // 15104
};

__constant__ float c_aw[3][3] = {{10.f,16.f,33.f},{30.f,62.f,59.f},{116.f,156.f,373.f}};
__constant__ float c_ah[3][3] = {{13.f,30.f,23.f},{61.f,45.f,119.f},{90.f,198.f,326.f}};

// ---- helpers (shared by pass1/pass2 -> bit-identical arithmetic) -----------
__device__ __forceinline__ unsigned fkey(float f) {
    unsigned u = __float_as_uint(f);
    return (u & 0x80000000u) ? ~u : (u | 0x80000000u);
}
__device__ __forceinline__ float fkey_inv(unsigned k) {
    return __uint_as_float((k & 0x80000000u) ? (k & 0x7fffffffu) : ~k);
}
__device__ __forceinline__ float sigm_rn(float v) {
    return __fdiv_rn(1.0f, __fadd_rn(1.0f, expf(-v)));
}
__device__ __forceinline__ float iou_rn(float px1, float py1, float px2, float py2, float pa,
                                        float gx1, float gy1, float gx2, float gy2, float ga) {
    float iw = __fsub_rn(fminf(gx2, px2), fmaxf(gx1, px1));
    float ih = __fsub_rn(fminf(gy2, py2), fmaxf(gy1, py1));
    float inter = __fmul_rn(iw, ih);
    float uni = __fadd_rn(ga, pa);
    return __fdiv_rn(inter, __fsub_rn(uni, inter));
}
__device__ __forceinline__ void decode_box(const float* __restrict__ o, int xg, int yg, float fg,
                                           float aw, float ah,
                                           float& px, float& py, float& pw, float& ph,
                                           float& x1, float& y1, float& x2, float& y2, float& pa) {
    px = __fdiv_rn(__fadd_rn(sigm_rn(o[0]), (float)xg), fg);
    py = __fdiv_rn(__fadd_rn(sigm_rn(o[1]), (float)yg), fg);
    pw = __fdiv_rn(__fmul_rn(expf(o[2]), aw), 608.0f);
    ph = __fdiv_rn(__fmul_rn(expf(o[3]), ah), 608.0f);
    float hw = __fmul_rn(pw, 0.5f), hh = __fmul_rn(ph, 0.5f);
    x1 = __fsub_rn(px, hw); x2 = __fadd_rn(px, hw);
    y1 = __fsub_rn(py, hh); y2 = __fadd_rn(py, hh);
    pa = __fmul_rn(pw, ph);
}
__device__ __forceinline__ void stage_gt(const float* __restrict__ gtb, int G, float* sg) {
    for (int t = threadIdx.x; t < G; t += blockDim.x) {
        float cx = gtb[t*4+0], cy = gtb[t*4+1], w = gtb[t*4+2], h = gtb[t*4+3];
        float hw = __fmul_rn(w, 0.5f), hh = __fmul_rn(h, 0.5f);
        sg[t*5+0] = __fsub_rn(cx, hw);
        sg[t*5+1] = __fsub_rn(cy, hh);
        sg[t*5+2] = __fadd_rn(cx, hw);
        sg[t*5+3] = __fadd_rn(cy, hh);
        sg[t*5+4] = __fmul_rn(w, h);
    }
}
__device__ __forceinline__ void scale_of_pblock(int bid, int& s, int& lb, int& gd, int& npos) {
    if (bid < PB0)            { s = 0; lb = bid;             gd = 76; npos = NP0; }
    else if (bid < PB0 + PB1) { s = 1; lb = bid - PB0;       gd = 38; npos = NP1; }
    else                      { s = 2; lb = bid - PB0 - PB1; gd = 19; npos = NP2; }
}

// ---- pass 1: per-gt global max IoU (as ordered uint keys) ------------------
__global__ __launch_bounds__(256) void k_pass1(const float* __restrict__ yo0,
                                               const float* __restrict__ yo1,
                                               const float* __restrict__ yo2,
                                               const float* __restrict__ gtb, int G,
                                               unsigned* __restrict__ gkeys) {
    __shared__ float sg[GMAX * 5];
    __shared__ unsigned smax[GMAX];
    int s, lb, gd, npos;
    scale_of_pblock(blockIdx.x, s, lb, gd, npos);
    const float* yo = (s == 0) ? yo0 : ((s == 1) ? yo1 : yo2);

    stage_gt(gtb, G, sg);
    for (int t = threadIdx.x; t < G; t += 256) smax[t] = 0u;
    __syncthreads();

    int p = lb * 256 + threadIdx.x;
    if (p < npos) {
        int a = p % 3;
        int q = p / 3;
        int xg = q % gd;
        int yg = (q / gd) % gd;
        float px, py, pw, ph, x1, y1, x2, y2, pa;
        decode_box(yo + (size_t)p * 85, xg, yg, (float)gd, c_aw[s][a], c_ah[s][a],
                   px, py, pw, ph, x1, y1, x2, y2, pa);
        int gi = threadIdx.x % G;   // stagger to spread LDS atomics across addresses
        for (int i = 0; i < G; i++) {
            const float* sp = sg + gi * 5;
            float v = iou_rn(x1, y1, x2, y2, pa, sp[0], sp[1], sp[2], sp[3], sp[4]);
            atomicMax(&smax[gi], fkey(v));
            gi++; if (gi == G) gi = 0;
        }
    }
    __syncthreads();
    for (int t = threadIdx.x; t < G; t += 256)
        atomicMax(&gkeys[s * GMAX + t], smax[t]);
}

// ---- streaming BCE reduction over all elements (coalesced float4) ----------
__global__ __launch_bounds__(256) void k_stream(const float* __restrict__ yo0, const float* __restrict__ yt0,
                                                const float* __restrict__ yo1, const float* __restrict__ yt1,
                                                const float* __restrict__ yo2, const float* __restrict__ yt2,
                                                float* __restrict__ acc) {
    int bid = blockIdx.x;
    int s, lb, Ns;
    const float* yo; const float* yt;
    if (bid < EB0)            { s = 0; lb = bid;             yo = yo0; yt = yt0; Ns = NE0; }
    else if (bid < EB0 + EB1) { s = 1; lb = bid - EB0;       yo = yo1; yt = yt1; Ns = NE1; }
    else                      { s = 2; lb = bid - EB0 - EB1; yo = yo2; yt = yt2; Ns = NE2; }

    int e0 = lb * 1024 + threadIdx.x * 4;
    float bo = 0.f, om = 0.f, bc = 0.f;
    if (e0 < Ns) {  // Ns is a multiple of 4, so e0..e0+3 all valid
        float4 o = *reinterpret_cast<const float4*>(yo + e0);
        float4 t = *reinterpret_cast<const float4*>(yt + e0);
        int r0 = e0 % 85;
        float ov[4] = {o.x, o.y, o.z, o.w};
        float tv[4] = {t.x, t.y, t.z, t.w};
#pragma unroll
        for (int j = 0; j < 4; j++) {
            int r = r0 + j; if (r >= 85) r -= 85;
            if (r >= 4) {
                // x = sigmoid(raw) in (0,1); bce-with-logits applied to x (faithful to ref)
                float x = __fdividef(1.f, 1.f + __expf(-ov[j]));
                float b = x - x * tv[j] + __logf(1.f + __expf(-x));
                if (r == 4) { bo += b; om += tv[j]; }
                else        { bc += b; }
            }
        }
    }
    // wave -> block reduction, one atomicAdd triple per block
    for (int off = 32; off > 0; off >>= 1) {
        bo += __shfl_down(bo, off);
        om += __shfl_down(om, off);
        bc += __shfl_down(bc, off);
    }
    __shared__ float sred[3][4];
    int wid = threadIdx.x >> 6, lane = threadIdx.x & 63;
    if (lane == 0) { sred[0][wid] = bo; sred[1][wid] = om; sred[2][wid] = bc; }
    __syncthreads();
    if (threadIdx.x == 0) {
        atomicAdd(&acc[s * 8 + 2], sred[0][0] + sred[0][1] + sred[0][2] + sred[0][3]);
        atomicAdd(&acc[s * 8 + 3], sred[1][0] + sred[1][1] + sred[1][2] + sred[1][3]);
        atomicAdd(&acc[s * 8 + 4], sred[2][0] + sred[2][1] + sred[2][2] + sred[2][3]);
    }
}

// ---- pass 2: assign mask (exact equality vs per-gt max) + sparse terms -----
__global__ __launch_bounds__(256) void k_pass2(const float* __restrict__ yo0, const float* __restrict__ yt0,
                                               const float* __restrict__ yo1, const float* __restrict__ yt1,
                                               const float* __restrict__ yo2, const float* __restrict__ yt2,
                                               const float* __restrict__ gtb, int G,
                                               const unsigned* __restrict__ gkeys,
                                               float* __restrict__ acc) {
    __shared__ float sg[GMAX * 5];
    __shared__ float smx[GMAX];
    int s, lb, gd, npos;
    scale_of_pblock(blockIdx.x, s, lb, gd, npos);
    const float* yo = (s == 0) ? yo0 : ((s == 1) ? yo1 : yo2);
    const float* yt = (s == 0) ? yt0 : ((s == 1) ? yt1 : yt2);

    stage_gt(gtb, G, sg);  // identical code as pass1 -> identical values
    for (int t = threadIdx.x; t < G; t += 256) smx[t] = fkey_inv(gkeys[s * GMAX + t]);
    __syncthreads();

    int p = lb * 256 + threadIdx.x;
    if (p < npos) {
        int a = p % 3;
        int q = p / 3;
        int xg = q % gd;
        int yg = (q / gd) % gd;
        float px, py, pw, ph, x1, y1, x2, y2, pa;
        decode_box(yo + (size_t)p * 85, xg, yg, (float)gd, c_aw[s][a], c_ah[s][a],
                   px, py, pw, ph, x1, y1, x2, y2, pa);
        bool asg = false;
        for (int gi = 0; gi < G; gi++) {
            const float* sp = sg + gi * 5;
            float v = iou_rn(x1, y1, x2, y2, pa, sp[0], sp[1], sp[2], sp[3], sp[4]);
            if (v == smx[gi]) { asg = true; break; }
        }
        if (asg) {
            const float* tp = yt + (size_t)p * 85;
            float t0 = tp[0], t1 = tp[1], t2 = tp[2], t3 = tp[3], t4 = tp[4];
            float bls = 2.0f - t2 * t3;
            float dx = t0 - px, dy = t1 - py, dw = t2 - pw, dh = t3 - ph;
            atomicAdd(&acc[s * 8 + 0], (dx * dx + dy * dy) * bls);   // xy
            atomicAdd(&acc[s * 8 + 1], (dw * dw + dh * dh) * bls);   // wh
            atomicAdd(&acc[s * 8 + 5], 1.0f - t4);                   // S correction
        }
    }
}

// ---- finalize ---------------------------------------------------------------
__global__ void k_fin(const float* __restrict__ acc, float* __restrict__ out) {
    if (threadIdx.x != 0 || blockIdx.x != 0) return;
    const float nposf[3] = {(float)NP0, (float)NP1, (float)NP2};
    float loss = 0.f;
    for (int s = 0; s < 3; s++) {
        const float* a = acc + s * 8;
        float xy = a[0], wh = a[1], bo = a[2], om = a[3], bc = a[4], sc = a[5];
        float np_ = nposf[s];
        float ob = bo / np_;                 // mean obj BCE
        float cb = bc / (np_ * 80.f);        // mean cls BCE
        loss += xy / 8.f + 0.5f * wh / 8.f + ob * (np_ - sc) / 8.f + om * cb / 8.f;
    }
    out[0] = loss;
}

extern "C" void kernel_launch(void* const* d_in, const int* in_sizes, int n_in,
                              void* d_out, int out_size, void* d_ws, size_t ws_size,
                              hipStream_t stream) {
    const float *yo0, *yt0, *yo1, *yt1, *yo2, *yt2;
    if (in_sizes[0] == in_sizes[1]) {
        // setup_inputs() dict order: y_out0, y_truth0, y_out1, y_truth1, y_out2, y_truth2
        yo0 = (const float*)d_in[0]; yt0 = (const float*)d_in[1];
        yo1 = (const float*)d_in[2]; yt1 = (const float*)d_in[3];
        yo2 = (const float*)d_in[4]; yt2 = (const float*)d_in[5];
    } else {
        // reference() signature order: y_out0..2, y_truth0..2
        yo0 = (const float*)d_in[0]; yo1 = (const float*)d_in[1]; yo2 = (const float*)d_in[2];
        yt0 = (const float*)d_in[3]; yt1 = (const float*)d_in[4]; yt2 = (const float*)d_in[5];
    }
    const float* gtb = (const float*)d_in[6];
    int G = in_sizes[6] / 4;
    if (G > GMAX) G = GMAX;

    unsigned* gkeys = (unsigned*)d_ws;
    float* acc = (float*)((char*)d_ws + 3 * GMAX * sizeof(unsigned));

    // zero max-keys (key 0 == below every real float) + accumulators, every call
    hipMemsetAsync(d_ws, 0, 3 * GMAX * sizeof(unsigned) + 3 * 8 * sizeof(float), stream);

    k_pass1 <<<PBT, 256, 0, stream>>>(yo0, yo1, yo2, gtb, G, gkeys);
    k_stream<<<EBT, 256, 0, stream>>>(yo0, yt0, yo1, yt1, yo2, yt2, acc);
    k_pass2 <<<PBT, 256, 0, stream>>>(yo0, yt0, yo1, yt1, yo2, yt2, gtb, G, gkeys, acc);
    k_fin   <<<1, 64, 0, stream>>>(acc, (float*)d_out);
}

// Round 2
// 96.252 us; speedup vs baseline: 6.5119x; 6.5119x over previous
//
#include <hip/hip_runtime.h>
#include <math.h>

#define GMAX 128

// ---- problem constants -----------------------------------------------------
enum {
    NP0 = 138624, NP1 = 34656, NP2 = 8664,           // positions per scale (B*g*g*3)
    PB0 = (NP0 + 255) / 256,                         // 542
    PB1 = (NP1 + 255) / 256,                         // 136
    PB2 = (NP2 + 255) / 256,                         // 34
    PBT = PB0 + PB1 + PB2,                           // 712
    NE0 = NP0 * 85, NE1 = NP1 * 85, NE2 = NP2 * 85,  // elements per scale
    NQ0 = NE0 / 4, NQ1 = NE1 / 4, NQ2 = NE2 / 4,     // float4 chunks (NPx % 4 == 0)
    SB0 = 1560, SB1 = 390, SB2 = 98,                 // stream blocks per scale
    SBT = SB0 + SB1 + SB2                            // 2048
};

__constant__ float c_aw[3][3] = {{10.f,16.f,33.f},{30.f,62.f,59.f},{116.f,156.f,373.f}};
__constant__ float c_ah[3][3] = {{13.f,30.f,23.f},{61.f,45.f,119.f},{90.f,198.f,326.f}};

// ---- helpers (shared by pass1/pass2 -> bit-identical arithmetic) -----------
__device__ __forceinline__ unsigned fkey(float f) {
    unsigned u = __float_as_uint(f);
    return (u & 0x80000000u) ? ~u : (u | 0x80000000u);
}
__device__ __forceinline__ float fkey_inv(unsigned k) {
    return __uint_as_float((k & 0x80000000u) ? (k & 0x7fffffffu) : ~k);
}
__device__ __forceinline__ float sigm_rn(float v) {
    return __fdiv_rn(1.0f, __fadd_rn(1.0f, expf(-v)));
}
__device__ __forceinline__ float iou_rn(float px1, float py1, float px2, float py2, float pa,
                                        float gx1, float gy1, float gx2, float gy2, float ga) {
    float iw = __fsub_rn(fminf(gx2, px2), fmaxf(gx1, px1));
    float ih = __fsub_rn(fminf(gy2, py2), fmaxf(gy1, py1));
    float inter = __fmul_rn(iw, ih);
    float uni = __fadd_rn(ga, pa);
    return __fdiv_rn(inter, __fsub_rn(uni, inter));
}
__device__ __forceinline__ void decode_box(const float* __restrict__ o, int xg, int yg, float fg,
                                           float aw, float ah,
                                           float& px, float& py, float& pw, float& ph,
                                           float& x1, float& y1, float& x2, float& y2, float& pa) {
    px = __fdiv_rn(__fadd_rn(sigm_rn(o[0]), (float)xg), fg);
    py = __fdiv_rn(__fadd_rn(sigm_rn(o[1]), (float)yg), fg);
    pw = __fdiv_rn(__fmul_rn(expf(o[2]), aw), 608.0f);
    ph = __fdiv_rn(__fmul_rn(expf(o[3]), ah), 608.0f);
    float hw = __fmul_rn(pw, 0.5f), hh = __fmul_rn(ph, 0.5f);
    x1 = __fsub_rn(px, hw); x2 = __fadd_rn(px, hw);
    y1 = __fsub_rn(py, hh); y2 = __fadd_rn(py, hh);
    pa = __fmul_rn(pw, ph);
}
__device__ __forceinline__ void stage_gt(const float* __restrict__ gtb, int G, float* sg) {
    for (int t = threadIdx.x; t < G; t += blockDim.x) {
        float cx = gtb[t*4+0], cy = gtb[t*4+1], w = gtb[t*4+2], h = gtb[t*4+3];
        float hw = __fmul_rn(w, 0.5f), hh = __fmul_rn(h, 0.5f);
        sg[t*5+0] = __fsub_rn(cx, hw);
        sg[t*5+1] = __fsub_rn(cy, hh);
        sg[t*5+2] = __fadd_rn(cx, hw);
        sg[t*5+3] = __fadd_rn(cy, hh);
        sg[t*5+4] = __fmul_rn(w, h);
    }
}
__device__ __forceinline__ void scale_of_pblock(int bid, int& s, int& lb, int& gd, int& npos) {
    if (bid < PB0)            { s = 0; lb = bid;             gd = 76; npos = NP0; }
    else if (bid < PB0 + PB1) { s = 1; lb = bid - PB0;       gd = 38; npos = NP1; }
    else                      { s = 2; lb = bid - PB0 - PB1; gd = 19; npos = NP2; }
}

// ---- pass 1: per-gt global max IoU (as ordered uint keys) ------------------
__global__ __launch_bounds__(256) void k_pass1(const float* __restrict__ yo0,
                                               const float* __restrict__ yo1,
                                               const float* __restrict__ yo2,
                                               const float* __restrict__ gtb, int G,
                                               unsigned* __restrict__ gkeys) {
    __shared__ float sg[GMAX * 5];
    __shared__ unsigned smax[GMAX];
    int s, lb, gd, npos;
    scale_of_pblock(blockIdx.x, s, lb, gd, npos);
    const float* yo = (s == 0) ? yo0 : ((s == 1) ? yo1 : yo2);

    stage_gt(gtb, G, sg);
    for (int t = threadIdx.x; t < G; t += 256) smax[t] = 0u;
    __syncthreads();

    int p = lb * 256 + threadIdx.x;
    if (p < npos) {
        int a = p % 3;
        int q = p / 3;
        int xg = q % gd;
        int yg = (q / gd) % gd;
        float px, py, pw, ph, x1, y1, x2, y2, pa;
        decode_box(yo + (size_t)p * 85, xg, yg, (float)gd, c_aw[s][a], c_ah[s][a],
                   px, py, pw, ph, x1, y1, x2, y2, pa);
        int gi = threadIdx.x % G;   // stagger to spread LDS atomics across banks
        for (int i = 0; i < G; i++) {
            const float* sp = sg + gi * 5;
            float v = iou_rn(x1, y1, x2, y2, pa, sp[0], sp[1], sp[2], sp[3], sp[4]);
            atomicMax(&smax[gi], fkey(v));
            gi++; if (gi == G) gi = 0;
        }
    }
    __syncthreads();
    for (int t = threadIdx.x; t < G; t += 256)
        atomicMax(&gkeys[s * GMAX + t], smax[t]);
}

// ---- streaming BCE reduction: grid-stride, partials to ws (NO atomics) -----
__global__ __launch_bounds__(256) void k_stream(const float* __restrict__ yo0, const float* __restrict__ yt0,
                                                const float* __restrict__ yo1, const float* __restrict__ yt1,
                                                const float* __restrict__ yo2, const float* __restrict__ yt2,
                                                float* __restrict__ partial) {
    int bid = blockIdx.x;
    int s, b0, nb, nq;
    const float* yo; const float* yt;
    if (bid < SB0)            { s = 0; b0 = bid;             nb = SB0; yo = yo0; yt = yt0; nq = NQ0; }
    else if (bid < SB0 + SB1) { s = 1; b0 = bid - SB0;       nb = SB1; yo = yo1; yt = yt1; nq = NQ1; }
    else                      { s = 2; b0 = bid - SB0 - SB1; nb = SB2; yo = yo2; yt = yt2; nq = NQ2; }
    (void)s;

    float bo = 0.f, om = 0.f, bc = 0.f;
    for (int qi = b0 * 256 + threadIdx.x; qi < nq; qi += nb * 256) {
        int e0 = qi * 4;
        float4 o = *reinterpret_cast<const float4*>(yo + e0);
        float4 t = *reinterpret_cast<const float4*>(yt + e0);
        int r0 = e0 % 85;
        float ov[4] = {o.x, o.y, o.z, o.w};
        float tv[4] = {t.x, t.y, t.z, t.w};
#pragma unroll
        for (int j = 0; j < 4; j++) {
            int r = r0 + j; if (r >= 85) r -= 85;
            if (r >= 4) {
                // x = sigmoid(raw) in (0,1); bce-with-logits applied to x (faithful to ref)
                float x = __fdividef(1.f, 1.f + __expf(-ov[j]));
                float b = x - x * tv[j] + __logf(1.f + __expf(-x));
                if (r == 4) { bo += b; om += tv[j]; }
                else        { bc += b; }
            }
        }
    }
    // wave -> block reduction, then ONE partial-slot write per block (no atomics)
    for (int off = 32; off > 0; off >>= 1) {
        bo += __shfl_down(bo, off);
        om += __shfl_down(om, off);
        bc += __shfl_down(bc, off);
    }
    __shared__ float sred[3][4];
    int wid = threadIdx.x >> 6, lane = threadIdx.x & 63;
    if (lane == 0) { sred[0][wid] = bo; sred[1][wid] = om; sred[2][wid] = bc; }
    __syncthreads();
    if (threadIdx.x == 0) {
        partial[bid * 4 + 0] = sred[0][0] + sred[0][1] + sred[0][2] + sred[0][3];
        partial[bid * 4 + 1] = sred[1][0] + sred[1][1] + sred[1][2] + sred[1][3];
        partial[bid * 4 + 2] = sred[2][0] + sred[2][1] + sred[2][2] + sred[2][3];
    }
}

// ---- pass 2: assign mask (exact equality vs per-gt max) + sparse terms -----
__global__ __launch_bounds__(256) void k_pass2(const float* __restrict__ yo0, const float* __restrict__ yt0,
                                               const float* __restrict__ yo1, const float* __restrict__ yt1,
                                               const float* __restrict__ yo2, const float* __restrict__ yt2,
                                               const float* __restrict__ gtb, int G,
                                               const unsigned* __restrict__ gkeys,
                                               float* __restrict__ acc) {
    __shared__ float sg[GMAX * 5];
    __shared__ float smx[GMAX];
    int s, lb, gd, npos;
    scale_of_pblock(blockIdx.x, s, lb, gd, npos);
    const float* yo = (s == 0) ? yo0 : ((s == 1) ? yo1 : yo2);
    const float* yt = (s == 0) ? yt0 : ((s == 1) ? yt1 : yt2);

    stage_gt(gtb, G, sg);  // identical code as pass1 -> identical values
    for (int t = threadIdx.x; t < G; t += 256) smx[t] = fkey_inv(gkeys[s * GMAX + t]);
    __syncthreads();

    int p = lb * 256 + threadIdx.x;
    if (p < npos) {
        int a = p % 3;
        int q = p / 3;
        int xg = q % gd;
        int yg = (q / gd) % gd;
        float px, py, pw, ph, x1, y1, x2, y2, pa;
        decode_box(yo + (size_t)p * 85, xg, yg, (float)gd, c_aw[s][a], c_ah[s][a],
                   px, py, pw, ph, x1, y1, x2, y2, pa);
        bool asg = false;
        for (int gi = 0; gi < G; gi++) {
            const float* sp = sg + gi * 5;
            float v = iou_rn(x1, y1, x2, y2, pa, sp[0], sp[1], sp[2], sp[3], sp[4]);
            if (v == smx[gi]) { asg = true; break; }
        }
        if (asg) {  // ~120 positions per scale -> negligible atomic traffic
            const float* tp = yt + (size_t)p * 85;
            float t0 = tp[0], t1 = tp[1], t2 = tp[2], t3 = tp[3], t4 = tp[4];
            float bls = 2.0f - t2 * t3;
            float dx = t0 - px, dy = t1 - py, dw = t2 - pw, dh = t3 - ph;
            atomicAdd(&acc[s * 8 + 0], (dx * dx + dy * dy) * bls);   // xy
            atomicAdd(&acc[s * 8 + 1], (dw * dw + dh * dh) * bls);   // wh
            atomicAdd(&acc[s * 8 + 5], 1.0f - t4);                   // S correction
        }
    }
}

// ---- finalize: reduce stream partials + combine ----------------------------
__global__ __launch_bounds__(256) void k_fin(const float* __restrict__ acc,
                                             const float* __restrict__ partial,
                                             float* __restrict__ out) {
    // per-thread accumulation of the 2048 partial triples, per scale
    float s0b = 0.f, s0m = 0.f, s0c = 0.f;
    float s1b = 0.f, s1m = 0.f, s1c = 0.f;
    float s2b = 0.f, s2m = 0.f, s2c = 0.f;
    for (int i = threadIdx.x; i < SBT; i += 256) {
        float b = partial[i * 4 + 0], m = partial[i * 4 + 1], c = partial[i * 4 + 2];
        if (i < SB0)            { s0b += b; s0m += m; s0c += c; }
        else if (i < SB0 + SB1) { s1b += b; s1m += m; s1c += c; }
        else                    { s2b += b; s2m += m; s2c += c; }
    }
    for (int off = 32; off > 0; off >>= 1) {
        s0b += __shfl_down(s0b, off); s0m += __shfl_down(s0m, off); s0c += __shfl_down(s0c, off);
        s1b += __shfl_down(s1b, off); s1m += __shfl_down(s1m, off); s1c += __shfl_down(s1c, off);
        s2b += __shfl_down(s2b, off); s2m += __shfl_down(s2m, off); s2c += __shfl_down(s2c, off);
    }
    __shared__ float sred[9][4];
    int wid = threadIdx.x >> 6, lane = threadIdx.x & 63;
    if (lane == 0) {
        sred[0][wid] = s0b; sred[1][wid] = s0m; sred[2][wid] = s0c;
        sred[3][wid] = s1b; sred[4][wid] = s1m; sred[5][wid] = s1c;
        sred[6][wid] = s2b; sred[7][wid] = s2m; sred[8][wid] = s2c;
    }
    __syncthreads();
    if (threadIdx.x == 0) {
        float bos[3], oms[3], bcs[3];
        bos[0] = sred[0][0]+sred[0][1]+sred[0][2]+sred[0][3];
        oms[0] = sred[1][0]+sred[1][1]+sred[1][2]+sred[1][3];
        bcs[0] = sred[2][0]+sred[2][1]+sred[2][2]+sred[2][3];
        bos[1] = sred[3][0]+sred[3][1]+sred[3][2]+sred[3][3];
        oms[1] = sred[4][0]+sred[4][1]+sred[4][2]+sred[4][3];
        bcs[1] = sred[5][0]+sred[5][1]+sred[5][2]+sred[5][3];
        bos[2] = sred[6][0]+sred[6][1]+sred[6][2]+sred[6][3];
        oms[2] = sred[7][0]+sred[7][1]+sred[7][2]+sred[7][3];
        bcs[2] = sred[8][0]+sred[8][1]+sred[8][2]+sred[8][3];
        const float nposf[3] = {(float)NP0, (float)NP1, (float)NP2};
        float loss = 0.f;
        for (int s = 0; s < 3; s++) {
            const float* a = acc + s * 8;
            float xy = a[0], wh = a[1], sc = a[5];
            float np_ = nposf[s];
            float ob = bos[s] / np_;                 // mean obj BCE
            float cb = bcs[s] / (np_ * 80.f);        // mean cls BCE
            loss += xy / 8.f + 0.5f * wh / 8.f + ob * (np_ - sc) / 8.f + oms[s] * cb / 8.f;
        }
        out[0] = loss;
    }
}

extern "C" void kernel_launch(void* const* d_in, const int* in_sizes, int n_in,
                              void* d_out, int out_size, void* d_ws, size_t ws_size,
                              hipStream_t stream) {
    const float *yo0, *yt0, *yo1, *yt1, *yo2, *yt2;
    if (in_sizes[0] == in_sizes[1]) {
        // setup_inputs() dict order: y_out0, y_truth0, y_out1, y_truth1, y_out2, y_truth2
        yo0 = (const float*)d_in[0]; yt0 = (const float*)d_in[1];
        yo1 = (const float*)d_in[2]; yt1 = (const float*)d_in[3];
        yo2 = (const float*)d_in[4]; yt2 = (const float*)d_in[5];
    } else {
        // reference() signature order: y_out0..2, y_truth0..2
        yo0 = (const float*)d_in[0]; yo1 = (const float*)d_in[1]; yo2 = (const float*)d_in[2];
        yt0 = (const float*)d_in[3]; yt1 = (const float*)d_in[4]; yt2 = (const float*)d_in[5];
    }
    const float* gtb = (const float*)d_in[6];
    int G = in_sizes[6] / 4;
    if (G > GMAX) G = GMAX;

    unsigned* gkeys = (unsigned*)d_ws;                                   // 3*GMAX u32
    float* acc = (float*)((char*)d_ws + 3 * GMAX * sizeof(unsigned));    // 3*8 f32
    float* partial = acc + 3 * 8;                                        // SBT*4 f32 (fully overwritten)

    // zero max-keys (key 0 == below every real float) + accumulators, every call
    hipMemsetAsync(d_ws, 0, 3 * GMAX * sizeof(unsigned) + 3 * 8 * sizeof(float), stream);

    // stream first: warms L2/L3 with the full arrays for pass1/pass2's strided reads
    k_stream<<<SBT, 256, 0, stream>>>(yo0, yt0, yo1, yt1, yo2, yt2, partial);
    k_pass1 <<<PBT, 256, 0, stream>>>(yo0, yo1, yo2, gtb, G, gkeys);
    k_pass2 <<<PBT, 256, 0, stream>>>(yo0, yt0, yo1, yt1, yo2, yt2, gtb, G, gkeys, acc);
    k_fin   <<<1, 256, 0, stream>>>(acc, partial, (float*)d_out);
}

// Round 3
// 92.642 us; speedup vs baseline: 6.7657x; 1.0390x over previous
//
#include <hip/hip_runtime.h>
#include <math.h>

#define GMAX 128

// ---- problem constants -----------------------------------------------------
enum {
    NP0 = 138624, NP1 = 34656, NP2 = 8664,           // positions per scale (B*g*g*3)
    PB0 = (NP0 + 255) / 256,                         // 542
    PB1 = (NP1 + 255) / 256,                         // 136
    PB2 = (NP2 + 255) / 256,                         // 34
    PBT = PB0 + PB1 + PB2,                           // 712
    NE0 = NP0 * 85, NE1 = NP1 * 85, NE2 = NP2 * 85,  // elements per scale
    NQ0 = NE0 / 4, NQ1 = NE1 / 4, NQ2 = NE2 / 4,     // float4 chunks (NEx % 4 == 0)
    CHT = 8,                                         // float4 chunks per thread
    SPB = 256 * CHT,                                 // chunks per block (2048)
    SB0 = (NQ0 + SPB - 1) / SPB,                     // 1439
    SB1 = (NQ1 + SPB - 1) / SPB,                     // 360
    SB2 = (NQ2 + SPB - 1) / SPB,                     // 90
    SBT = SB0 + SB1 + SB2                            // 1889
};

__constant__ float c_aw[3][3] = {{10.f,16.f,33.f},{30.f,62.f,59.f},{116.f,156.f,373.f}};
__constant__ float c_ah[3][3] = {{13.f,30.f,23.f},{61.f,45.f,119.f},{90.f,198.f,326.f}};

// ---- helpers (shared by pass1/pass2 -> bit-identical arithmetic) -----------
__device__ __forceinline__ unsigned fkey(float f) {
    unsigned u = __float_as_uint(f);
    return (u & 0x80000000u) ? ~u : (u | 0x80000000u);
}
__device__ __forceinline__ float fkey_inv(unsigned k) {
    return __uint_as_float((k & 0x80000000u) ? (k & 0x7fffffffu) : ~k);
}
__device__ __forceinline__ float sigm_rn(float v) {
    return __fdiv_rn(1.0f, __fadd_rn(1.0f, expf(-v)));
}
__device__ __forceinline__ float iou_rn(float px1, float py1, float px2, float py2, float pa,
                                        float gx1, float gy1, float gx2, float gy2, float ga) {
    float iw = __fsub_rn(fminf(gx2, px2), fmaxf(gx1, px1));
    float ih = __fsub_rn(fminf(gy2, py2), fmaxf(gy1, py1));
    float inter = __fmul_rn(iw, ih);
    float uni = __fadd_rn(ga, pa);
    return __fdiv_rn(inter, __fsub_rn(uni, inter));
}
__device__ __forceinline__ void decode_box(const float* __restrict__ o, int xg, int yg, float fg,
                                           float aw, float ah,
                                           float& px, float& py, float& pw, float& ph,
                                           float& x1, float& y1, float& x2, float& y2, float& pa) {
    px = __fdiv_rn(__fadd_rn(sigm_rn(o[0]), (float)xg), fg);
    py = __fdiv_rn(__fadd_rn(sigm_rn(o[1]), (float)yg), fg);
    pw = __fdiv_rn(__fmul_rn(expf(o[2]), aw), 608.0f);
    ph = __fdiv_rn(__fmul_rn(expf(o[3]), ah), 608.0f);
    float hw = __fmul_rn(pw, 0.5f), hh = __fmul_rn(ph, 0.5f);
    x1 = __fsub_rn(px, hw); x2 = __fadd_rn(px, hw);
    y1 = __fsub_rn(py, hh); y2 = __fadd_rn(py, hh);
    pa = __fmul_rn(pw, ph);
}
__device__ __forceinline__ void stage_gt(const float* __restrict__ gtb, int G, float* sg) {
    for (int t = threadIdx.x; t < G; t += blockDim.x) {
        float cx = gtb[t*4+0], cy = gtb[t*4+1], w = gtb[t*4+2], h = gtb[t*4+3];
        float hw = __fmul_rn(w, 0.5f), hh = __fmul_rn(h, 0.5f);
        sg[t*5+0] = __fsub_rn(cx, hw);
        sg[t*5+1] = __fsub_rn(cy, hh);
        sg[t*5+2] = __fadd_rn(cx, hw);
        sg[t*5+3] = __fadd_rn(cy, hh);
        sg[t*5+4] = __fmul_rn(w, h);
    }
}
__device__ __forceinline__ void scale_of_pblock(int bid, int& s, int& lb, int& gd, int& npos) {
    if (bid < PB0)            { s = 0; lb = bid;             gd = 76; npos = NP0; }
    else if (bid < PB0 + PB1) { s = 1; lb = bid - PB0;       gd = 38; npos = NP1; }
    else                      { s = 2; lb = bid - PB0 - PB1; gd = 19; npos = NP2; }
}

// ---- pass 1: per-gt global max IoU (as ordered uint keys) ------------------
__global__ __launch_bounds__(256) void k_pass1(const float* __restrict__ yo0,
                                               const float* __restrict__ yo1,
                                               const float* __restrict__ yo2,
                                               const float* __restrict__ gtb, int G,
                                               unsigned* __restrict__ gkeys) {
    __shared__ float sg[GMAX * 5];
    __shared__ unsigned smax[GMAX];
    int s, lb, gd, npos;
    scale_of_pblock(blockIdx.x, s, lb, gd, npos);
    const float* yo = (s == 0) ? yo0 : ((s == 1) ? yo1 : yo2);

    stage_gt(gtb, G, sg);
    for (int t = threadIdx.x; t < G; t += 256) smax[t] = 0u;
    __syncthreads();

    int p = lb * 256 + threadIdx.x;
    if (p < npos) {
        int a = p % 3;
        int q = p / 3;
        int xg = q % gd;
        int yg = (q / gd) % gd;
        float px, py, pw, ph, x1, y1, x2, y2, pa;
        decode_box(yo + (size_t)p * 85, xg, yg, (float)gd, c_aw[s][a], c_ah[s][a],
                   px, py, pw, ph, x1, y1, x2, y2, pa);
        int gi = threadIdx.x % G;   // stagger to spread LDS atomics across banks
        for (int i = 0; i < G; i++) {
            const float* sp = sg + gi * 5;
            float v = iou_rn(x1, y1, x2, y2, pa, sp[0], sp[1], sp[2], sp[3], sp[4]);
            atomicMax(&smax[gi], fkey(v));
            gi++; if (gi == G) gi = 0;
        }
    }
    __syncthreads();
    for (int t = threadIdx.x; t < G; t += 256)
        atomicMax(&gkeys[s * GMAX + t], smax[t]);
}

// ---- streaming BCE reduction: unrolled batch loads, partials to ws ---------
__global__ __launch_bounds__(256) void k_stream(const float* __restrict__ yo0, const float* __restrict__ yt0,
                                                const float* __restrict__ yo1, const float* __restrict__ yt1,
                                                const float* __restrict__ yo2, const float* __restrict__ yt2,
                                                float* __restrict__ partial,
                                                unsigned* __restrict__ gkeys,
                                                float* __restrict__ acc) {
    int bid = blockIdx.x;
    // block 0 zeroes the ws accumulators consumed by pass1/pass2 (stream-ordered
    // after this kernel completes) -> replaces the pathological tiny memset fill
    if (bid == 0) {
        for (int t = threadIdx.x; t < 3 * GMAX; t += 256) gkeys[t] = 0u;
        if (threadIdx.x < 24) acc[threadIdx.x] = 0.f;
    }

    int s, b0, nq;
    const float* yo; const float* yt;
    if (bid < SB0)            { s = 0; b0 = bid;             yo = yo0; yt = yt0; nq = NQ0; }
    else if (bid < SB0 + SB1) { s = 1; b0 = bid - SB0;       yo = yo1; yt = yt1; nq = NQ1; }
    else                      { s = 2; b0 = bid - SB0 - SB1; yo = yo2; yt = yt2; nq = NQ2; }
    (void)s;

    // issue all 16 loads up-front (clamped addresses, masked accumulation)
    int base = b0 * SPB + threadIdx.x;
    float4 o4[CHT], t4[CHT];
    int qv[CHT]; bool val[CHT];
#pragma unroll
    for (int j = 0; j < CHT; j++) {
        int qi = base + j * 256;
        val[j] = qi < nq;
        int qc = val[j] ? qi : (nq - 1);
        qv[j] = qc;
        o4[j] = *reinterpret_cast<const float4*>(yo + (size_t)qc * 4);
        t4[j] = *reinterpret_cast<const float4*>(yt + (size_t)qc * 4);
    }

    float bo = 0.f, om = 0.f, bc = 0.f;
#pragma unroll
    for (int j = 0; j < CHT; j++) {
        if (!val[j]) continue;
        int r0 = (qv[j] * 4) % 85;
        float ov[4] = {o4[j].x, o4[j].y, o4[j].z, o4[j].w};
        float tv[4] = {t4[j].x, t4[j].y, t4[j].z, t4[j].w};
#pragma unroll
        for (int k2 = 0; k2 < 4; k2++) {
            int r = r0 + k2; if (r >= 85) r -= 85;
            if (r >= 4) {
                // x = sigmoid(raw) in (0,1); bce-with-logits applied to x (faithful to ref)
                float x = __fdividef(1.f, 1.f + __expf(-ov[k2]));
                float b = x - x * tv[k2] + __logf(1.f + __expf(-x));
                if (r == 4) { bo += b; om += tv[k2]; }
                else        { bc += b; }
            }
        }
    }

    // wave -> block reduction, then ONE partial-slot write per block (no atomics)
    for (int off = 32; off > 0; off >>= 1) {
        bo += __shfl_down(bo, off);
        om += __shfl_down(om, off);
        bc += __shfl_down(bc, off);
    }
    __shared__ float sred[3][4];
    int wid = threadIdx.x >> 6, lane = threadIdx.x & 63;
    if (lane == 0) { sred[0][wid] = bo; sred[1][wid] = om; sred[2][wid] = bc; }
    __syncthreads();
    if (threadIdx.x == 0) {
        partial[bid * 4 + 0] = sred[0][0] + sred[0][1] + sred[0][2] + sred[0][3];
        partial[bid * 4 + 1] = sred[1][0] + sred[1][1] + sred[1][2] + sred[1][3];
        partial[bid * 4 + 2] = sred[2][0] + sred[2][1] + sred[2][2] + sred[2][3];
    }
}

// ---- pass 2: assign mask (exact equality vs per-gt max) + sparse terms -----
__global__ __launch_bounds__(256) void k_pass2(const float* __restrict__ yo0, const float* __restrict__ yt0,
                                               const float* __restrict__ yo1, const float* __restrict__ yt1,
                                               const float* __restrict__ yo2, const float* __restrict__ yt2,
                                               const float* __restrict__ gtb, int G,
                                               const unsigned* __restrict__ gkeys,
                                               float* __restrict__ acc) {
    __shared__ float sg[GMAX * 5];
    __shared__ float smx[GMAX];
    int s, lb, gd, npos;
    scale_of_pblock(blockIdx.x, s, lb, gd, npos);
    const float* yo = (s == 0) ? yo0 : ((s == 1) ? yo1 : yo2);
    const float* yt = (s == 0) ? yt0 : ((s == 1) ? yt1 : yt2);

    stage_gt(gtb, G, sg);  // identical code as pass1 -> identical values
    for (int t = threadIdx.x; t < G; t += 256) smx[t] = fkey_inv(gkeys[s * GMAX + t]);
    __syncthreads();

    int p = lb * 256 + threadIdx.x;
    if (p < npos) {
        int a = p % 3;
        int q = p / 3;
        int xg = q % gd;
        int yg = (q / gd) % gd;
        float px, py, pw, ph, x1, y1, x2, y2, pa;
        decode_box(yo + (size_t)p * 85, xg, yg, (float)gd, c_aw[s][a], c_ah[s][a],
                   px, py, pw, ph, x1, y1, x2, y2, pa);
        bool asg = false;
        for (int gi = 0; gi < G; gi++) {
            const float* sp = sg + gi * 5;
            float v = iou_rn(x1, y1, x2, y2, pa, sp[0], sp[1], sp[2], sp[3], sp[4]);
            if (v == smx[gi]) { asg = true; break; }
        }
        if (asg) {  // ~120 positions per scale -> negligible atomic traffic
            const float* tp = yt + (size_t)p * 85;
            float t0 = tp[0], t1 = tp[1], t2 = tp[2], t3 = tp[3], t4 = tp[4];
            float bls = 2.0f - t2 * t3;
            float dx = t0 - px, dy = t1 - py, dw = t2 - pw, dh = t3 - ph;
            atomicAdd(&acc[s * 8 + 0], (dx * dx + dy * dy) * bls);   // xy
            atomicAdd(&acc[s * 8 + 1], (dw * dw + dh * dh) * bls);   // wh
            atomicAdd(&acc[s * 8 + 5], 1.0f - t4);                   // S correction
        }
    }
}

// ---- finalize: reduce stream partials + combine ----------------------------
__global__ __launch_bounds__(256) void k_fin(const float* __restrict__ acc,
                                             const float* __restrict__ partial,
                                             float* __restrict__ out) {
    // per-thread accumulation of the partial triples, per scale
    float s0b = 0.f, s0m = 0.f, s0c = 0.f;
    float s1b = 0.f, s1m = 0.f, s1c = 0.f;
    float s2b = 0.f, s2m = 0.f, s2c = 0.f;
    for (int i = threadIdx.x; i < SBT; i += 256) {
        float b = partial[i * 4 + 0], m = partial[i * 4 + 1], c = partial[i * 4 + 2];
        if (i < SB0)            { s0b += b; s0m += m; s0c += c; }
        else if (i < SB0 + SB1) { s1b += b; s1m += m; s1c += c; }
        else                    { s2b += b; s2m += m; s2c += c; }
    }
    for (int off = 32; off > 0; off >>= 1) {
        s0b += __shfl_down(s0b, off); s0m += __shfl_down(s0m, off); s0c += __shfl_down(s0c, off);
        s1b += __shfl_down(s1b, off); s1m += __shfl_down(s1m, off); s1c += __shfl_down(s1c, off);
        s2b += __shfl_down(s2b, off); s2m += __shfl_down(s2m, off); s2c += __shfl_down(s2c, off);
    }
    __shared__ float sred[9][4];
    int wid = threadIdx.x >> 6, lane = threadIdx.x & 63;
    if (lane == 0) {
        sred[0][wid] = s0b; sred[1][wid] = s0m; sred[2][wid] = s0c;
        sred[3][wid] = s1b; sred[4][wid] = s1m; sred[5][wid] = s1c;
        sred[6][wid] = s2b; sred[7][wid] = s2m; sred[8][wid] = s2c;
    }
    __syncthreads();
    if (threadIdx.x == 0) {
        float bos[3], oms[3], bcs[3];
        bos[0] = sred[0][0]+sred[0][1]+sred[0][2]+sred[0][3];
        oms[0] = sred[1][0]+sred[1][1]+sred[1][2]+sred[1][3];
        bcs[0] = sred[2][0]+sred[2][1]+sred[2][2]+sred[2][3];
        bos[1] = sred[3][0]+sred[3][1]+sred[3][2]+sred[3][3];
        oms[1] = sred[4][0]+sred[4][1]+sred[4][2]+sred[4][3];
        bcs[1] = sred[5][0]+sred[5][1]+sred[5][2]+sred[5][3];
        bos[2] = sred[6][0]+sred[6][1]+sred[6][2]+sred[6][3];
        oms[2] = sred[7][0]+sred[7][1]+sred[7][2]+sred[7][3];
        bcs[2] = sred[8][0]+sred[8][1]+sred[8][2]+sred[8][3];
        const float nposf[3] = {(float)NP0, (float)NP1, (float)NP2};
        float loss = 0.f;
        for (int s = 0; s < 3; s++) {
            const float* a = acc + s * 8;
            float xy = a[0], wh = a[1], sc = a[5];
            float np_ = nposf[s];
            float ob = bos[s] / np_;                 // mean obj BCE
            float cb = bcs[s] / (np_ * 80.f);        // mean cls BCE
            loss += xy / 8.f + 0.5f * wh / 8.f + ob * (np_ - sc) / 8.f + oms[s] * cb / 8.f;
        }
        out[0] = loss;
    }
}

extern "C" void kernel_launch(void* const* d_in, const int* in_sizes, int n_in,
                              void* d_out, int out_size, void* d_ws, size_t ws_size,
                              hipStream_t stream) {
    const float *yo0, *yt0, *yo1, *yt1, *yo2, *yt2;
    if (in_sizes[0] == in_sizes[1]) {
        // setup_inputs() dict order: y_out0, y_truth0, y_out1, y_truth1, y_out2, y_truth2
        yo0 = (const float*)d_in[0]; yt0 = (const float*)d_in[1];
        yo1 = (const float*)d_in[2]; yt1 = (const float*)d_in[3];
        yo2 = (const float*)d_in[4]; yt2 = (const float*)d_in[5];
    } else {
        // reference() signature order: y_out0..2, y_truth0..2
        yo0 = (const float*)d_in[0]; yo1 = (const float*)d_in[1]; yo2 = (const float*)d_in[2];
        yt0 = (const float*)d_in[3]; yt1 = (const float*)d_in[4]; yt2 = (const float*)d_in[5];
    }
    const float* gtb = (const float*)d_in[6];
    int G = in_sizes[6] / 4;
    if (G > GMAX) G = GMAX;

    unsigned* gkeys = (unsigned*)d_ws;                                   // 3*GMAX u32
    float* acc = (float*)((char*)d_ws + 3 * GMAX * sizeof(unsigned));    // 3*8 f32
    float* partial = acc + 3 * 8;                                        // SBT*4 f32 (fully overwritten)

    // stream first: zeros gkeys/acc (block 0) and warms L2/L3 for pass1/pass2
    k_stream<<<SBT, 256, 0, stream>>>(yo0, yt0, yo1, yt1, yo2, yt2, partial, gkeys, acc);
    k_pass1 <<<PBT, 256, 0, stream>>>(yo0, yo1, yo2, gtb, G, gkeys);
    k_pass2 <<<PBT, 256, 0, stream>>>(yo0, yt0, yo1, yt1, yo2, yt2, gtb, G, gkeys, acc);
    k_fin   <<<1, 256, 0, stream>>>(acc, partial, (float*)d_out);
}

// Round 4
// 86.755 us; speedup vs baseline: 7.2248x; 1.0679x over previous
//
#include <hip/hip_runtime.h>
#include <math.h>

#define GMAX 128

// ---- problem constants -----------------------------------------------------
enum {
    NP0 = 138624, NP1 = 34656, NP2 = 8664,           // positions per scale (B*g*g*3)
    PB0 = (NP0 + 255) / 256,                         // 542
    PB1 = (NP1 + 255) / 256,                         // 136
    PB2 = (NP2 + 255) / 256,                         // 34
    PBT = PB0 + PB1 + PB2,                           // 712
    NE0 = NP0 * 85, NE1 = NP1 * 85, NE2 = NP2 * 85,  // elements per scale
    NQ0 = NE0 / 4, NQ1 = NE1 / 4, NQ2 = NE2 / 4,     // float4 chunks (NEx % 4 == 0)
    SB0 = 1560, SB1 = 390, SB2 = 98,                 // stream blocks per scale
    SBT = SB0 + SB1 + SB2                            // 2048
};

__constant__ float c_aw[3][3] = {{10.f,16.f,33.f},{30.f,62.f,59.f},{116.f,156.f,373.f}};
__constant__ float c_ah[3][3] = {{13.f,30.f,23.f},{61.f,45.f,119.f},{90.f,198.f,326.f}};

// ---- helpers (shared by pass1/pass2 -> bit-identical arithmetic) -----------
__device__ __forceinline__ unsigned fkey(float f) {
    unsigned u = __float_as_uint(f);
    return (u & 0x80000000u) ? ~u : (u | 0x80000000u);
}
__device__ __forceinline__ float fkey_inv(unsigned k) {
    return __uint_as_float((k & 0x80000000u) ? (k & 0x7fffffffu) : ~k);
}
__device__ __forceinline__ float sigm_rn(float v) {
    return __fdiv_rn(1.0f, __fadd_rn(1.0f, expf(-v)));
}
__device__ __forceinline__ float iou_rn(float px1, float py1, float px2, float py2, float pa,
                                        float gx1, float gy1, float gx2, float gy2, float ga) {
    float iw = __fsub_rn(fminf(gx2, px2), fmaxf(gx1, px1));
    float ih = __fsub_rn(fminf(gy2, py2), fmaxf(gy1, py1));
    float inter = __fmul_rn(iw, ih);
    float uni = __fadd_rn(ga, pa);
    return __fdiv_rn(inter, __fsub_rn(uni, inter));
}
__device__ __forceinline__ void decode_box(const float* __restrict__ o, int xg, int yg, float fg,
                                           float aw, float ah,
                                           float& px, float& py, float& pw, float& ph,
                                           float& x1, float& y1, float& x2, float& y2, float& pa) {
    px = __fdiv_rn(__fadd_rn(sigm_rn(o[0]), (float)xg), fg);
    py = __fdiv_rn(__fadd_rn(sigm_rn(o[1]), (float)yg), fg);
    pw = __fdiv_rn(__fmul_rn(expf(o[2]), aw), 608.0f);
    ph = __fdiv_rn(__fmul_rn(expf(o[3]), ah), 608.0f);
    float hw = __fmul_rn(pw, 0.5f), hh = __fmul_rn(ph, 0.5f);
    x1 = __fsub_rn(px, hw); x2 = __fadd_rn(px, hw);
    y1 = __fsub_rn(py, hh); y2 = __fadd_rn(py, hh);
    pa = __fmul_rn(pw, ph);
}
__device__ __forceinline__ void stage_gt(const float* __restrict__ gtb, int G, float* sg) {
    for (int t = threadIdx.x; t < G; t += blockDim.x) {
        float cx = gtb[t*4+0], cy = gtb[t*4+1], w = gtb[t*4+2], h = gtb[t*4+3];
        float hw = __fmul_rn(w, 0.5f), hh = __fmul_rn(h, 0.5f);
        sg[t*5+0] = __fsub_rn(cx, hw);
        sg[t*5+1] = __fsub_rn(cy, hh);
        sg[t*5+2] = __fadd_rn(cx, hw);
        sg[t*5+3] = __fadd_rn(cy, hh);
        sg[t*5+4] = __fmul_rn(w, h);
    }
}
__device__ __forceinline__ void scale_of_pblock(int bid, int& s, int& lb, int& gd, int& npos) {
    if (bid < PB0)            { s = 0; lb = bid;             gd = 76; npos = NP0; }
    else if (bid < PB0 + PB1) { s = 1; lb = bid - PB0;       gd = 38; npos = NP1; }
    else                      { s = 2; lb = bid - PB0 - PB1; gd = 19; npos = NP2; }
}

// ---- zero ws accumulators (replaces pathological runtime fill) -------------
__global__ __launch_bounds__(256) void k_zero(unsigned* __restrict__ gkeys,
                                              float* __restrict__ acc) {
    for (int t = threadIdx.x; t < 3 * GMAX; t += 256) gkeys[t] = 0u;
    if (threadIdx.x < 24) acc[threadIdx.x] = 0.f;
}

// ---- fused: pass1 (first PBT blocks, latency-bound) + stream (BW-bound) ----
__global__ __launch_bounds__(256) void k_main(const float* __restrict__ yo0, const float* __restrict__ yt0,
                                              const float* __restrict__ yo1, const float* __restrict__ yt1,
                                              const float* __restrict__ yo2, const float* __restrict__ yt2,
                                              const float* __restrict__ gtb, int G,
                                              unsigned* __restrict__ gkeys,
                                              float* __restrict__ partial) {
    int bid = blockIdx.x;
    if (bid < PBT) {
        // ---------------- pass 1: per-gt global max IoU ----------------
        __shared__ float sg[GMAX * 5];
        __shared__ unsigned smax[GMAX];
        int s, lb, gd, npos;
        scale_of_pblock(bid, s, lb, gd, npos);
        const float* yo = (s == 0) ? yo0 : ((s == 1) ? yo1 : yo2);

        stage_gt(gtb, G, sg);
        for (int t = threadIdx.x; t < G; t += 256) smax[t] = 0u;
        __syncthreads();

        int p = lb * 256 + threadIdx.x;
        if (p < npos) {
            int a = p % 3;
            int q = p / 3;
            int xg = q % gd;
            int yg = (q / gd) % gd;
            float px, py, pw, ph, x1, y1, x2, y2, pa;
            decode_box(yo + (size_t)p * 85, xg, yg, (float)gd, c_aw[s][a], c_ah[s][a],
                       px, py, pw, ph, x1, y1, x2, y2, pa);
            int gi = threadIdx.x % G;   // stagger LDS atomics across banks
            for (int i = 0; i < G; i++) {
                const float* sp = sg + gi * 5;
                float v = iou_rn(x1, y1, x2, y2, pa, sp[0], sp[1], sp[2], sp[3], sp[4]);
                atomicMax(&smax[gi], fkey(v));
                gi++; if (gi == G) gi = 0;
            }
        }
        __syncthreads();
        for (int t = threadIdx.x; t < G; t += 256)
            atomicMax(&gkeys[s * GMAX + t], smax[t]);
        return;
    }

    // ---------------- stream: BCE reduction (proven R2 grid-stride) --------
    int sbid = bid - PBT;
    int s, b0, nb, nq;
    const float* yo; const float* yt;
    if (sbid < SB0)            { s = 0; b0 = sbid;             nb = SB0; yo = yo0; yt = yt0; nq = NQ0; }
    else if (sbid < SB0 + SB1) { s = 1; b0 = sbid - SB0;       nb = SB1; yo = yo1; yt = yt1; nq = NQ1; }
    else                       { s = 2; b0 = sbid - SB0 - SB1; nb = SB2; yo = yo2; yt = yt2; nq = NQ2; }
    (void)s;

    float bo = 0.f, om = 0.f, bc = 0.f;
    for (int qi = b0 * 256 + threadIdx.x; qi < nq; qi += nb * 256) {
        int e0 = qi * 4;
        float4 o = *reinterpret_cast<const float4*>(yo + e0);
        float4 t = *reinterpret_cast<const float4*>(yt + e0);
        int r0 = e0 % 85;
        float ov[4] = {o.x, o.y, o.z, o.w};
        float tv[4] = {t.x, t.y, t.z, t.w};
#pragma unroll
        for (int j = 0; j < 4; j++) {
            int r = r0 + j; if (r >= 85) r -= 85;
            if (r >= 4) {
                // x = sigmoid(raw); bce-with-logits applied to x (faithful to ref).
                // log(1+exp(-x)) for x in (0,1) via cubic interpolant (|err|<2e-4):
                float x = __fdividef(1.f, 1.f + __expf(-ov[j]));
                float fx = __fmaf_rn(__fmaf_rn(__fmaf_rn(-0.0088613f, x, 0.1296426f),
                                               x, -0.5006668f), x, 0.6931472f);
                float b = __fmaf_rn(-x, tv[j], x) + fx;
                if (r == 4) { bo += b; om += tv[j]; }
                else        { bc += b; }
            }
        }
    }
    // wave -> block reduction, then ONE partial-slot write per block (no atomics)
    for (int off = 32; off > 0; off >>= 1) {
        bo += __shfl_down(bo, off);
        om += __shfl_down(om, off);
        bc += __shfl_down(bc, off);
    }
    __shared__ float sred[3][4];
    int wid = threadIdx.x >> 6, lane = threadIdx.x & 63;
    if (lane == 0) { sred[0][wid] = bo; sred[1][wid] = om; sred[2][wid] = bc; }
    __syncthreads();
    if (threadIdx.x == 0) {
        partial[sbid * 4 + 0] = sred[0][0] + sred[0][1] + sred[0][2] + sred[0][3];
        partial[sbid * 4 + 1] = sred[1][0] + sred[1][1] + sred[1][2] + sred[1][3];
        partial[sbid * 4 + 2] = sred[2][0] + sred[2][1] + sred[2][2] + sred[2][3];
    }
}

// ---- pass 2: assign mask (exact equality vs per-gt max) + sparse terms -----
__global__ __launch_bounds__(256) void k_pass2(const float* __restrict__ yo0, const float* __restrict__ yt0,
                                               const float* __restrict__ yo1, const float* __restrict__ yt1,
                                               const float* __restrict__ yo2, const float* __restrict__ yt2,
                                               const float* __restrict__ gtb, int G,
                                               const unsigned* __restrict__ gkeys,
                                               float* __restrict__ acc) {
    __shared__ float sg[GMAX * 5];
    __shared__ float smx[GMAX];
    int s, lb, gd, npos;
    scale_of_pblock(blockIdx.x, s, lb, gd, npos);
    const float* yo = (s == 0) ? yo0 : ((s == 1) ? yo1 : yo2);
    const float* yt = (s == 0) ? yt0 : ((s == 1) ? yt1 : yt2);

    stage_gt(gtb, G, sg);  // identical code as pass1 -> identical values
    for (int t = threadIdx.x; t < G; t += 256) smx[t] = fkey_inv(gkeys[s * GMAX + t]);
    __syncthreads();

    int p = lb * 256 + threadIdx.x;
    if (p < npos) {
        int a = p % 3;
        int q = p / 3;
        int xg = q % gd;
        int yg = (q / gd) % gd;
        float px, py, pw, ph, x1, y1, x2, y2, pa;
        decode_box(yo + (size_t)p * 85, xg, yg, (float)gd, c_aw[s][a], c_ah[s][a],
                   px, py, pw, ph, x1, y1, x2, y2, pa);
        bool asg = false;
        for (int gi = 0; gi < G; gi++) {
            const float* sp = sg + gi * 5;
            float v = iou_rn(x1, y1, x2, y2, pa, sp[0], sp[1], sp[2], sp[3], sp[4]);
            if (v == smx[gi]) { asg = true; break; }
        }
        if (asg) {  // ~120 positions per scale -> negligible atomic traffic
            const float* tp = yt + (size_t)p * 85;
            float t0 = tp[0], t1 = tp[1], t2 = tp[2], t3 = tp[3], t4 = tp[4];
            float bls = 2.0f - t2 * t3;
            float dx = t0 - px, dy = t1 - py, dw = t2 - pw, dh = t3 - ph;
            atomicAdd(&acc[s * 8 + 0], (dx * dx + dy * dy) * bls);   // xy
            atomicAdd(&acc[s * 8 + 1], (dw * dw + dh * dh) * bls);   // wh
            atomicAdd(&acc[s * 8 + 5], 1.0f - t4);                   // S correction
        }
    }
}

// ---- finalize: reduce stream partials + combine ----------------------------
__global__ __launch_bounds__(256) void k_fin(const float* __restrict__ acc,
                                             const float* __restrict__ partial,
                                             float* __restrict__ out) {
    float s0b = 0.f, s0m = 0.f, s0c = 0.f;
    float s1b = 0.f, s1m = 0.f, s1c = 0.f;
    float s2b = 0.f, s2m = 0.f, s2c = 0.f;
    for (int i = threadIdx.x; i < SBT; i += 256) {
        float b = partial[i * 4 + 0], m = partial[i * 4 + 1], c = partial[i * 4 + 2];
        if (i < SB0)            { s0b += b; s0m += m; s0c += c; }
        else if (i < SB0 + SB1) { s1b += b; s1m += m; s1c += c; }
        else                    { s2b += b; s2m += m; s2c += c; }
    }
    for (int off = 32; off > 0; off >>= 1) {
        s0b += __shfl_down(s0b, off); s0m += __shfl_down(s0m, off); s0c += __shfl_down(s0c, off);
        s1b += __shfl_down(s1b, off); s1m += __shfl_down(s1m, off); s1c += __shfl_down(s1c, off);
        s2b += __shfl_down(s2b, off); s2m += __shfl_down(s2m, off); s2c += __shfl_down(s2c, off);
    }
    __shared__ float sred[9][4];
    int wid = threadIdx.x >> 6, lane = threadIdx.x & 63;
    if (lane == 0) {
        sred[0][wid] = s0b; sred[1][wid] = s0m; sred[2][wid] = s0c;
        sred[3][wid] = s1b; sred[4][wid] = s1m; sred[5][wid] = s1c;
        sred[6][wid] = s2b; sred[7][wid] = s2m; sred[8][wid] = s2c;
    }
    __syncthreads();
    if (threadIdx.x == 0) {
        float bos[3], oms[3], bcs[3];
        bos[0] = sred[0][0]+sred[0][1]+sred[0][2]+sred[0][3];
        oms[0] = sred[1][0]+sred[1][1]+sred[1][2]+sred[1][3];
        bcs[0] = sred[2][0]+sred[2][1]+sred[2][2]+sred[2][3];
        bos[1] = sred[3][0]+sred[3][1]+sred[3][2]+sred[3][3];
        oms[1] = sred[4][0]+sred[4][1]+sred[4][2]+sred[4][3];
        bcs[1] = sred[5][0]+sred[5][1]+sred[5][2]+sred[5][3];
        bos[2] = sred[6][0]+sred[6][1]+sred[6][2]+sred[6][3];
        oms[2] = sred[7][0]+sred[7][1]+sred[7][2]+sred[7][3];
        bcs[2] = sred[8][0]+sred[8][1]+sred[8][2]+sred[8][3];
        const float nposf[3] = {(float)NP0, (float)NP1, (float)NP2};
        float loss = 0.f;
        for (int s = 0; s < 3; s++) {
            const float* a = acc + s * 8;
            float xy = a[0], wh = a[1], sc = a[5];
            float np_ = nposf[s];
            float ob = bos[s] / np_;                 // mean obj BCE
            float cb = bcs[s] / (np_ * 80.f);        // mean cls BCE
            loss += xy / 8.f + 0.5f * wh / 8.f + ob * (np_ - sc) / 8.f + oms[s] * cb / 8.f;
        }
        out[0] = loss;
    }
}

extern "C" void kernel_launch(void* const* d_in, const int* in_sizes, int n_in,
                              void* d_out, int out_size, void* d_ws, size_t ws_size,
                              hipStream_t stream) {
    const float *yo0, *yt0, *yo1, *yt1, *yo2, *yt2;
    if (in_sizes[0] == in_sizes[1]) {
        // setup_inputs() dict order: y_out0, y_truth0, y_out1, y_truth1, y_out2, y_truth2
        yo0 = (const float*)d_in[0]; yt0 = (const float*)d_in[1];
        yo1 = (const float*)d_in[2]; yt1 = (const float*)d_in[3];
        yo2 = (const float*)d_in[4]; yt2 = (const float*)d_in[5];
    } else {
        // reference() signature order: y_out0..2, y_truth0..2
        yo0 = (const float*)d_in[0]; yo1 = (const float*)d_in[1]; yo2 = (const float*)d_in[2];
        yt0 = (const float*)d_in[3]; yt1 = (const float*)d_in[4]; yt2 = (const float*)d_in[5];
    }
    const float* gtb = (const float*)d_in[6];
    int G = in_sizes[6] / 4;
    if (G > GMAX) G = GMAX;

    unsigned* gkeys = (unsigned*)d_ws;                                   // 3*GMAX u32
    float* acc = (float*)((char*)d_ws + 3 * GMAX * sizeof(unsigned));    // 3*8 f32
    float* partial = acc + 3 * 8;                                        // SBT*4 f32 (fully overwritten)

    k_zero <<<1, 256, 0, stream>>>(gkeys, acc);
    k_main <<<PBT + SBT, 256, 0, stream>>>(yo0, yt0, yo1, yt1, yo2, yt2, gtb, G, gkeys, partial);
    k_pass2<<<PBT, 256, 0, stream>>>(yo0, yt0, yo1, yt1, yo2, yt2, gtb, G, gkeys, acc);
    k_fin  <<<1, 256, 0, stream>>>(acc, partial, (float*)d_out);
}